// Round 1
// baseline (504.764 us; speedup 1.0000x reference)
//
#include <hip/hip_runtime.h>
#include <float.h>

// B=2, N=2048, M=2048, DIM=1024, H=16, DH=64, INNER=1024
// out = softmax(mask(causal((x@Wq * s) @ (cond@Wkv_k)^T))) @ (cond@Wkv_v) @ Wo + bo

typedef __bf16 bf16x8 __attribute__((ext_vector_type(8)));
typedef float f32x4 __attribute__((ext_vector_type(4)));
typedef unsigned short u16x4 __attribute__((ext_vector_type(4)));
typedef unsigned int u32x4 __attribute__((ext_vector_type(4)));
typedef int i32x4 __attribute__((ext_vector_type(4)));

#define DEV static __device__ __forceinline__

DEV unsigned short f2bf(float f) {
  union { float f; unsigned u; } v; v.f = f;
  unsigned r = v.u + 0x7FFFu + ((v.u >> 16) & 1u);
  return (unsigned short)(r >> 16);
}
DEV float bf2f(unsigned short u) {
  union { unsigned u; float f; } v; v.u = ((unsigned)u) << 16; return v.f;
}
DEV unsigned pack2(float a, float b) {
  return (unsigned)f2bf(a) | ((unsigned)f2bf(b) << 16);
}
DEV bf16x8 ldb8(const unsigned short* p) { return *reinterpret_cast<const bf16x8*>(p); }
DEV f32x4 zero4() { f32x4 z = {0.f, 0.f, 0.f, 0.f}; return z; }

// ---------- cast f32 -> bf16, 4 elems/thread ----------
__global__ __launch_bounds__(256) void cast_kernel(const float* __restrict__ in,
                                                   unsigned short* __restrict__ out, int n4) {
  int t = blockIdx.x * 256 + threadIdx.x;
  if (t >= n4) return;
  f32x4 v = *reinterpret_cast<const f32x4*>(in + (size_t)t * 4);
  u16x4 o;
  o[0] = f2bf(v[0]); o[1] = f2bf(v[1]); o[2] = f2bf(v[2]); o[3] = f2bf(v[3]);
  *reinterpret_cast<u16x4*>(out + (size_t)t * 4) = o;
}

// ---------- transpose + cast weight: in [1024 x N_] f32 -> out [N_ x 1024] bf16 ----------
__global__ __launch_bounds__(256) void transpose_cast_kernel(const float* __restrict__ in,
                                                             unsigned short* __restrict__ out,
                                                             int N_, int total) {
  int t = blockIdx.x * 256 + threadIdx.x;
  if (t >= total) return;
  int k = t & 1023;   // K is always 1024
  int n = t >> 10;
  out[t] = f2bf(in[(size_t)k * N_ + n]);  // out[n][k], coalesced writes
}

// ---------- zero-LDS MFMA GEMM: C[M][Ncols] = A[M][K] @ Bt[Ncols][K]^T ----------
// 256 threads, 4 waves in 2x2; block tile 128x128; each wave 64x64 (4x4 16x16 frags).
// MODE 0: Q-proj  -> out_q[bh][n][d] bf16, scaled by DH^-0.5
// MODE 1: KV-proj -> cols<1024: K[bh][m][d] bf16 ; cols>=1024: V^T[bh][d][m] bf16
// MODE 2: O-proj  -> outF[m][c] f32 + bias[c]
template<int MODE>
__global__ __launch_bounds__(256) void gemm_kernel(const unsigned short* __restrict__ Ab,
                                                   const unsigned short* __restrict__ Bt,
                                                   unsigned short* __restrict__ o16a,
                                                   unsigned short* __restrict__ o16b,
                                                   float* __restrict__ oF,
                                                   const float* __restrict__ bias,
                                                   int K_) {
  const int tid = threadIdx.x;
  const int lane = tid & 63;
  const int w = tid >> 6;
  const int li = lane & 15, hi = lane >> 4;
  const int wr = w >> 1, wc = w & 1;
  const int gm0 = blockIdx.y * 128 + wr * 64;
  const int gn0 = blockIdx.x * 128 + wc * 64;

  f32x4 acc[4][4];
#pragma unroll
  for (int i = 0; i < 4; ++i)
#pragma unroll
    for (int j = 0; j < 4; ++j) acc[i][j] = zero4();

  const unsigned short* ap = Ab + (size_t)(gm0 + li) * K_ + hi * 8;
  const unsigned short* bp = Bt + (size_t)(gn0 + li) * K_ + hi * 8;

  for (int kt = 0; kt < K_; kt += 32) {
    bf16x8 af[4], bfv[4];
#pragma unroll
    for (int i = 0; i < 4; ++i) af[i] = ldb8(ap + (size_t)(i * 16) * K_ + kt);
#pragma unroll
    for (int i = 0; i < 4; ++i) bfv[i] = ldb8(bp + (size_t)(i * 16) * K_ + kt);
#pragma unroll
    for (int mi = 0; mi < 4; ++mi)
#pragma unroll
      for (int ni = 0; ni < 4; ++ni)
        acc[mi][ni] = __builtin_amdgcn_mfma_f32_16x16x32_bf16(af[mi], bfv[ni], acc[mi][ni], 0, 0, 0);
  }

  // epilogue: lane holds D[row=4*hi+r][col=li] per 16x16 frag (m89-verified layout)
#pragma unroll
  for (int mi = 0; mi < 4; ++mi) {
#pragma unroll
    for (int ni = 0; ni < 4; ++ni) {
      const int gc = gn0 + ni * 16 + li;
#pragma unroll
      for (int r = 0; r < 4; ++r) {
        const int gm = gm0 + mi * 16 + 4 * hi + r;
        float v = acc[mi][ni][r];
        if constexpr (MODE == 0) {
          v *= 0.125f;  // DH^-0.5
          const int b = gm >> 11, n = gm & 2047, hh = gc >> 6, d = gc & 63;
          o16a[((size_t)((b << 4) + hh) * 2048 + n) * 64 + d] = f2bf(v);
        } else if constexpr (MODE == 1) {
          const int b = gm >> 11, mr = gm & 2047;
          if (gc < 1024) {
            const int hh = gc >> 6, d = gc & 63;
            o16a[((size_t)((b << 4) + hh) * 2048 + mr) * 64 + d] = f2bf(v);
          } else {
            const int c2 = gc - 1024, hh = c2 >> 6, d = c2 & 63;
            o16b[(size_t)((b << 4) + hh) * 131072 + (size_t)d * 2048 + mr] = f2bf(v);
          }
        } else {
          oF[(size_t)gm * 1024 + gc] = v + bias[gc];
        }
      }
    }
  }
}

// ---------- per-(b,h,d) mean of V (for fully-masked rows -> uniform softmax) ----------
__global__ __launch_bounds__(256) void vmean_kernel(const unsigned short* __restrict__ Vt,
                                                    float* __restrict__ Vmean) {
  const int bh = blockIdx.x;  // 0..31
  const int t = threadIdx.x;
  const int d = t >> 2, part = t & 3;
  const unsigned short* p = Vt + (size_t)bh * 131072 + (size_t)d * 2048 + part * 512;
  float s = 0.f;
  for (int i = 0; i < 512; i += 4) {
    u16x4 v = *reinterpret_cast<const u16x4*>(p + i);
    s += bf2f(v[0]) + bf2f(v[1]) + bf2f(v[2]) + bf2f(v[3]);
  }
  __shared__ float red[256];
  red[t] = s;
  __syncthreads();
  if (part == 0)
    Vmean[bh * 64 + d] = (red[t] + red[t + 1] + red[t + 2] + red[t + 3]) * (1.f / 2048.f);
}

// ---------- flash cross-attention: 1 wave = 16 q-rows, KV tiles of 32, no LDS ----------
// S^T = K·Q^T via mfma (lane holds S[kv=4*hi+r][q=li]); P relayout via shuffles; O = P·V
// with V^T read directly from global as the B-operand.
__global__ __launch_bounds__(256) void attn_kernel(const unsigned short* __restrict__ Qb,
                                                   const unsigned short* __restrict__ Kb,
                                                   const unsigned short* __restrict__ Vt,
                                                   const int* __restrict__ mask,
                                                   const float* __restrict__ Vmean,
                                                   unsigned short* __restrict__ O) {
  const int wid = (blockIdx.x * 256 + threadIdx.x) >> 6;  // 0..4095
  const int lane = threadIdx.x & 63;
  const int li = lane & 15, hi = lane >> 4;
  const int b = wid >> 11;
  const int h = (wid >> 7) & 15;
  const int qt = wid & 127;
  const int q0 = qt << 4;
  const int bh = (b << 4) + h;
  const unsigned short* Qp = Qb + (size_t)bh * 131072 + (size_t)q0 * 64;
  const unsigned short* Kp = Kb + (size_t)bh * 131072;
  const unsigned short* Vp = Vt + (size_t)bh * 131072;
  const int* mp = mask + b * 2048;

  // Q as B-operand (col=q=li, k=d): contiguous 16B per lane
  const bf16x8 qf0 = ldb8(Qp + li * 64 + hi * 8);
  const bf16x8 qf1 = ldb8(Qp + li * 64 + 32 + hi * 8);

  f32x4 o0 = zero4(), o1 = zero4(), o2 = zero4(), o3 = zero4();
  float m_run = -FLT_MAX, l_run = 0.f;
  const int q = q0 + li;
  const int ntiles = ((q0 + 15) >> 5) + 1;  // causal: kv <= q0+15

  for (int it = 0; it < ntiles; ++it) {
    const int kv0 = it << 5;
    const unsigned short* kp = Kp + (size_t)kv0 * 64;
    // K as A-operand (row=kv=li, k=d)
    const bf16x8 k00 = ldb8(kp + li * 64 + hi * 8);
    const bf16x8 k01 = ldb8(kp + li * 64 + 32 + hi * 8);
    const bf16x8 k10 = ldb8(kp + (16 + li) * 64 + hi * 8);
    const bf16x8 k11 = ldb8(kp + (16 + li) * 64 + 32 + hi * 8);
    f32x4 st0 = zero4(), st1 = zero4();
    st0 = __builtin_amdgcn_mfma_f32_16x16x32_bf16(k00, qf0, st0, 0, 0, 0);
    st0 = __builtin_amdgcn_mfma_f32_16x16x32_bf16(k01, qf1, st0, 0, 0, 0);
    st1 = __builtin_amdgcn_mfma_f32_16x16x32_bf16(k10, qf0, st1, 0, 0, 0);
    st1 = __builtin_amdgcn_mfma_f32_16x16x32_bf16(k11, qf1, st1, 0, 0, 0);

    const i32x4 mk0 = *reinterpret_cast<const i32x4*>(mp + kv0 + 4 * hi);
    const i32x4 mk1 = *reinterpret_cast<const i32x4*>(mp + kv0 + 16 + 4 * hi);

    float p0[4], p1[4];
    float tmax = -FLT_MAX;
#pragma unroll
    for (int r = 0; r < 4; ++r) {
      const int kv = kv0 + 4 * hi + r;
      const float s = (mk0[r] != 0 && kv <= q) ? st0[r] : -FLT_MAX;
      p0[r] = s; tmax = fmaxf(tmax, s);
    }
#pragma unroll
    for (int r = 0; r < 4; ++r) {
      const int kv = kv0 + 16 + 4 * hi + r;
      const float s = (mk1[r] != 0 && kv <= q) ? st1[r] : -FLT_MAX;
      p1[r] = s; tmax = fmaxf(tmax, s);
    }
    // row-max across the 4 lanes sharing q=li
    tmax = fmaxf(tmax, __shfl_xor(tmax, 16, 64));
    tmax = fmaxf(tmax, __shfl_xor(tmax, 32, 64));
    const float m_new = fmaxf(m_run, tmax);
    const float resc = __expf(m_run - m_new);  // exp(0)=1 when both -FLT_MAX (all-masked)
    float rsum = 0.f;
#pragma unroll
    for (int r = 0; r < 4; ++r) { p0[r] = __expf(p0[r] - m_new); rsum += p0[r]; }
#pragma unroll
    for (int r = 0; r < 4; ++r) { p1[r] = __expf(p1[r] - m_new); rsum += p1[r]; }
    rsum += __shfl_xor(rsum, 16, 64);
    rsum += __shfl_xor(rsum, 32, 64);
    l_run = l_run * resc + rsum;
    m_run = m_new;

    // rescale O: factor per accumulator row q=4*hi+r, fetched from lane (4*hi+r)
    const float f0 = __shfl(resc, 4 * hi + 0, 64);
    const float f1 = __shfl(resc, 4 * hi + 1, 64);
    const float f2 = __shfl(resc, 4 * hi + 2, 64);
    const float f3 = __shfl(resc, 4 * hi + 3, 64);
    o0[0] *= f0; o0[1] *= f1; o0[2] *= f2; o0[3] *= f3;
    o1[0] *= f0; o1[1] *= f1; o1[2] *= f2; o1[3] *= f3;
    o2[0] *= f0; o2[1] *= f1; o2[2] *= f2; o2[3] *= f3;
    o3[0] *= f0; o3[1] *= f1; o3[2] *= f2; o3[3] *= f3;

    // P relayout: S^T regs (kv=4*hi+r per 16-tile) -> A-operand (kv=8*hi+e).
    // Target needs tile T=hi>>1 from src lane li+32*(hi&1) (+16 for 2nd half).
    const unsigned pk00 = pack2(p0[0], p0[1]);
    const unsigned pk01 = pack2(p0[2], p0[3]);
    const unsigned pk10 = pack2(p1[0], p1[1]);
    const unsigned pk11 = pack2(p1[2], p1[3]);
    const int s0 = li + ((hi & 1) << 5);
    const int s1 = s0 + 16;
    const unsigned a0 = (unsigned)__shfl((int)pk00, s0, 64);
    const unsigned b0 = (unsigned)__shfl((int)pk10, s0, 64);
    const unsigned a1 = (unsigned)__shfl((int)pk01, s0, 64);
    const unsigned b1 = (unsigned)__shfl((int)pk11, s0, 64);
    const unsigned a2 = (unsigned)__shfl((int)pk00, s1, 64);
    const unsigned b2 = (unsigned)__shfl((int)pk10, s1, 64);
    const unsigned a3 = (unsigned)__shfl((int)pk01, s1, 64);
    const unsigned b3 = (unsigned)__shfl((int)pk11, s1, 64);
    const bool lo = (hi < 2);
    u32x4 pw;
    pw[0] = lo ? a0 : b0;
    pw[1] = lo ? a1 : b1;
    pw[2] = lo ? a2 : b2;
    pw[3] = lo ? a3 : b3;
    const bf16x8 pf = __builtin_bit_cast(bf16x8, pw);

    // V^T as B-operand (col=d=nc*16+li, k=kv): contiguous 16B per lane
    const bf16x8 vf0 = ldb8(Vp + (size_t)(0 * 16 + li) * 2048 + kv0 + hi * 8);
    const bf16x8 vf1 = ldb8(Vp + (size_t)(1 * 16 + li) * 2048 + kv0 + hi * 8);
    const bf16x8 vf2 = ldb8(Vp + (size_t)(2 * 16 + li) * 2048 + kv0 + hi * 8);
    const bf16x8 vf3 = ldb8(Vp + (size_t)(3 * 16 + li) * 2048 + kv0 + hi * 8);
    o0 = __builtin_amdgcn_mfma_f32_16x16x32_bf16(pf, vf0, o0, 0, 0, 0);
    o1 = __builtin_amdgcn_mfma_f32_16x16x32_bf16(pf, vf1, o1, 0, 0, 0);
    o2 = __builtin_amdgcn_mfma_f32_16x16x32_bf16(pf, vf2, o2, 0, 0, 0);
    o3 = __builtin_amdgcn_mfma_f32_16x16x32_bf16(pf, vf3, o3, 0, 0, 0);
  }

  // epilogue: normalize; fully-masked rows -> mean(V) (reference uniform-softmax semantics)
  unsigned short* Op = O + ((size_t)(b * 2048 + q0)) * 1024 + h * 64;
#pragma unroll
  for (int r = 0; r < 4; ++r) {
    const int qrow = 4 * hi + r;
    const float ls = __shfl(l_run, qrow, 64);
    const float mr = __shfl(m_run, qrow, 64);
    const bool dead = (mr == -FLT_MAX);
    const float inv = dead ? 0.f : (1.f / ls);
    const float v0 = dead ? Vmean[bh * 64 + 0 + li] : o0[r] * inv;
    const float v1 = dead ? Vmean[bh * 64 + 16 + li] : o1[r] * inv;
    const float v2 = dead ? Vmean[bh * 64 + 32 + li] : o2[r] * inv;
    const float v3 = dead ? Vmean[bh * 64 + 48 + li] : o3[r] * inv;
    unsigned short* row = Op + (size_t)qrow * 1024;
    row[0 + li] = f2bf(v0);
    row[16 + li] = f2bf(v1);
    row[32 + li] = f2bf(v2);
    row[48 + li] = f2bf(v3);
  }
}

extern "C" void kernel_launch(void* const* d_in, const int* in_sizes, int n_in,
                              void* d_out, int out_size, void* d_ws, size_t ws_size,
                              hipStream_t stream) {
  const float* x    = (const float*)d_in[0];
  const float* cond = (const float*)d_in[1];
  const int*   mask = (const int*)d_in[2];
  const float* Wq   = (const float*)d_in[3];
  const float* Wkv  = (const float*)d_in[4];
  const float* Wo   = (const float*)d_in[5];
  const float* bo   = (const float*)d_in[6];
  float* out = (float*)d_out;

  char* ws = (char*)d_ws;
  const size_t MB = 1u << 20;
  unsigned short* xb    = (unsigned short*)(ws + 0 * MB);    // [4096][1024] bf16, 8MB
  unsigned short* condb = (unsigned short*)(ws + 8 * MB);    // [4096][1024] bf16, 8MB
  unsigned short* WqT   = (unsigned short*)(ws + 16 * MB);   // [1024][1024] bf16, 2MB
  unsigned short* WkvT  = (unsigned short*)(ws + 18 * MB);   // [2048][1024] bf16, 4MB
  unsigned short* WoT   = (unsigned short*)(ws + 22 * MB);   // [1024][1024] bf16, 2MB
  unsigned short* Qb    = (unsigned short*)(ws + 24 * MB);   // [32][2048][64] bf16, 8MB
  unsigned short* Kb    = (unsigned short*)(ws + 32 * MB);   // [32][2048][64] bf16, 8MB
  unsigned short* Vt    = (unsigned short*)(ws + 40 * MB);   // [32][64][2048] bf16, 8MB
  unsigned short* Ob    = (unsigned short*)(ws + 48 * MB);   // [4096][1024] bf16, 8MB
  float*          Vmean = (float*)(ws + 56 * MB);            // [32][64] f32, 8KB
  (void)in_sizes; (void)n_in; (void)out_size; (void)ws_size;

  // 1-2: cast activations to bf16
  cast_kernel<<<4096, 256, 0, stream>>>(x, xb, 1048576);
  cast_kernel<<<4096, 256, 0, stream>>>(cond, condb, 1048576);
  // 3-5: transpose+cast weights to [N][K] bf16
  transpose_cast_kernel<<<4096, 256, 0, stream>>>(Wq, WqT, 1024, 1048576);
  transpose_cast_kernel<<<8192, 256, 0, stream>>>(Wkv, WkvT, 2048, 2097152);
  transpose_cast_kernel<<<4096, 256, 0, stream>>>(Wo, WoT, 1024, 1048576);
  // 6: Q projection (scaled)
  gemm_kernel<0><<<dim3(8, 32), 256, 0, stream>>>(xb, WqT, Qb, nullptr, nullptr, nullptr, 1024);
  // 7: KV projection (K normal layout, V transposed)
  gemm_kernel<1><<<dim3(16, 32), 256, 0, stream>>>(condb, WkvT, Kb, Vt, nullptr, nullptr, 1024);
  // 8: V column means (fully-masked-row fallback)
  vmean_kernel<<<32, 256, 0, stream>>>(Vt, Vmean);
  // 9: flash attention
  attn_kernel<<<1024, 256, 0, stream>>>(Qb, Kb, Vt, mask, Vmean, Ob);
  // 10: output projection + bias
  gemm_kernel<2><<<dim3(8, 32), 256, 0, stream>>>(Ob, WoT, nullptr, nullptr, out, bo, 1024);
}

// Round 2
// 392.619 us; speedup vs baseline: 1.2856x; 1.2856x over previous
//
#include <hip/hip_runtime.h>
#include <float.h>

// B=2, N=2048, M=2048, DIM=1024, H=16, DH=64, INNER=1024
// out = softmax(mask(causal((x@Wq * s) @ (cond@Wkv_k)^T))) @ (cond@Wkv_v) @ Wo + bo

typedef __bf16 bf16x8 __attribute__((ext_vector_type(8)));
typedef float f32x4 __attribute__((ext_vector_type(4)));
typedef unsigned short u16x4 __attribute__((ext_vector_type(4)));
typedef unsigned int u32x4 __attribute__((ext_vector_type(4)));
typedef int i32x4 __attribute__((ext_vector_type(4)));

#define DEV static __device__ __forceinline__

DEV unsigned short f2bf(float f) {
  union { float f; unsigned u; } v; v.f = f;
  unsigned r = v.u + 0x7FFFu + ((v.u >> 16) & 1u);
  return (unsigned short)(r >> 16);
}
DEV float bf2f(unsigned short u) {
  union { unsigned u; float f; } v; v.u = ((unsigned)u) << 16; return v.f;
}
DEV unsigned pack2(float a, float b) {
  return (unsigned)f2bf(a) | ((unsigned)f2bf(b) << 16);
}
DEV bf16x8 ldb8(const unsigned short* p) { return *reinterpret_cast<const bf16x8*>(p); }
DEV f32x4 zero4() { f32x4 z = {0.f, 0.f, 0.f, 0.f}; return z; }

// ---------- cast f32 -> bf16, 4 elems/thread ----------
__global__ __launch_bounds__(256) void cast_kernel(const float* __restrict__ in,
                                                   unsigned short* __restrict__ out, int n4) {
  int t = blockIdx.x * 256 + threadIdx.x;
  if (t >= n4) return;
  f32x4 v = *reinterpret_cast<const f32x4*>(in + (size_t)t * 4);
  u16x4 o;
  o[0] = f2bf(v[0]); o[1] = f2bf(v[1]); o[2] = f2bf(v[2]); o[3] = f2bf(v[3]);
  *reinterpret_cast<u16x4*>(out + (size_t)t * 4) = o;
}

// ---------- transpose + cast weight: in [1024 x N_] f32 -> out [N_ x 1024] bf16 ----------
__global__ __launch_bounds__(256) void transpose_cast_kernel(const float* __restrict__ in,
                                                             unsigned short* __restrict__ out,
                                                             int N_, int total) {
  int t = blockIdx.x * 256 + threadIdx.x;
  if (t >= total) return;
  int k = t & 1023;   // K is always 1024
  int n = t >> 10;
  out[t] = f2bf(in[(size_t)k * N_ + n]);  // out[n][k], coalesced writes
}

// ---------- zero-LDS MFMA GEMM: C[M][Ncols] = A[M][K] @ Bt[Ncols][K]^T ----------
// 256 threads, 4 waves in 2x2; block tile 128x128; each wave 64x64 (4x4 16x16 frags).
// MODE 0: Q-proj  -> out_q[bh][n][d] bf16, scaled by DH^-0.5
// MODE 1: KV-proj -> cols<1024: K[bh][m][d] bf16 ; cols>=1024: V^T[bh][d][m] bf16
// MODE 2: O-proj  -> outF[m][c] f32 + bias[c]
template<int MODE>
__global__ __launch_bounds__(256) void gemm_kernel(const unsigned short* __restrict__ Ab,
                                                   const unsigned short* __restrict__ Bt,
                                                   unsigned short* __restrict__ o16a,
                                                   unsigned short* __restrict__ o16b,
                                                   float* __restrict__ oF,
                                                   const float* __restrict__ bias,
                                                   int K_) {
  const int tid = threadIdx.x;
  const int lane = tid & 63;
  const int w = tid >> 6;
  const int li = lane & 15, hi = lane >> 4;
  const int wr = w >> 1, wc = w & 1;
  const int gm0 = blockIdx.y * 128 + wr * 64;
  const int gn0 = blockIdx.x * 128 + wc * 64;

  f32x4 acc[4][4];
#pragma unroll
  for (int i = 0; i < 4; ++i)
#pragma unroll
    for (int j = 0; j < 4; ++j) acc[i][j] = zero4();

  const unsigned short* ap = Ab + (size_t)(gm0 + li) * K_ + hi * 8;
  const unsigned short* bp = Bt + (size_t)(gn0 + li) * K_ + hi * 8;

  for (int kt = 0; kt < K_; kt += 32) {
    bf16x8 af[4], bfv[4];
#pragma unroll
    for (int i = 0; i < 4; ++i) af[i] = ldb8(ap + (size_t)(i * 16) * K_ + kt);
#pragma unroll
    for (int i = 0; i < 4; ++i) bfv[i] = ldb8(bp + (size_t)(i * 16) * K_ + kt);
#pragma unroll
    for (int mi = 0; mi < 4; ++mi)
#pragma unroll
      for (int ni = 0; ni < 4; ++ni)
        acc[mi][ni] = __builtin_amdgcn_mfma_f32_16x16x32_bf16(af[mi], bfv[ni], acc[mi][ni], 0, 0, 0);
  }

  // epilogue: lane holds D[row=4*hi+r][col=li] per 16x16 frag (m89-verified layout)
#pragma unroll
  for (int mi = 0; mi < 4; ++mi) {
#pragma unroll
    for (int ni = 0; ni < 4; ++ni) {
      const int gc = gn0 + ni * 16 + li;
#pragma unroll
      for (int r = 0; r < 4; ++r) {
        const int gm = gm0 + mi * 16 + 4 * hi + r;
        float v = acc[mi][ni][r];
        if constexpr (MODE == 0) {
          v *= 0.125f;  // DH^-0.5
          const int b = gm >> 11, n = gm & 2047, hh = gc >> 6, d = gc & 63;
          o16a[((size_t)((b << 4) + hh) * 2048 + n) * 64 + d] = f2bf(v);
        } else if constexpr (MODE == 1) {
          const int b = gm >> 11, mr = gm & 2047;
          if (gc < 1024) {
            const int hh = gc >> 6, d = gc & 63;
            o16a[((size_t)((b << 4) + hh) * 2048 + mr) * 64 + d] = f2bf(v);
          } else {
            const int c2 = gc - 1024, hh = c2 >> 6, d = c2 & 63;
            o16b[(size_t)((b << 4) + hh) * 131072 + (size_t)d * 2048 + mr] = f2bf(v);
          }
        } else {
          oF[(size_t)gm * 1024 + gc] = v + bias[gc];
        }
      }
    }
  }
}

// ---------- per-(b,h,d) mean of V (for fully-masked rows -> uniform softmax) ----------
__global__ __launch_bounds__(256) void vmean_kernel(const unsigned short* __restrict__ Vt,
                                                    float* __restrict__ Vmean) {
  const int bh = blockIdx.x;  // 0..31
  const int t = threadIdx.x;
  const int d = t >> 2, part = t & 3;
  const unsigned short* p = Vt + (size_t)bh * 131072 + (size_t)d * 2048 + part * 512;
  float s = 0.f;
  for (int i = 0; i < 512; i += 4) {
    u16x4 v = *reinterpret_cast<const u16x4*>(p + i);
    s += bf2f(v[0]) + bf2f(v[1]) + bf2f(v[2]) + bf2f(v[3]);
  }
  __shared__ float red[256];
  red[t] = s;
  __syncthreads();
  if (part == 0)
    Vmean[bh * 64 + d] = (red[t] + red[t + 1] + red[t + 2] + red[t + 3]) * (1.f / 2048.f);
}

// ---------- flash cross-attention v2 ----------
// 1 wave = 32 q-rows (2 q-groups of 16 sharing every K/V fragment), KV tiles of 32, no LDS.
// XCD-affinity swizzle: each of the 8 XCDs owns 4 (b,h) pairs -> K/V/Q (3MB) fit its 4MB L2.
// Longest-work-first qchunk order to fill the causal drain tail.
// S^T = K·Q^T via mfma (lane holds S[kv=4*hi+r][q=li]); P relayout via shuffles; O = P·V
// with V^T read directly from global as the B-operand.
__global__ __launch_bounds__(256) void attn_kernel(const unsigned short* __restrict__ Qb,
                                                   const unsigned short* __restrict__ Kb,
                                                   const unsigned short* __restrict__ Vt,
                                                   const int* __restrict__ mask,
                                                   const float* __restrict__ Vmean,
                                                   unsigned short* __restrict__ O) {
  const int bid = blockIdx.x;              // 0..511
  const int xcd = bid & 7;                 // MI355X round-robins blocks across 8 XCDs
  const int s = bid >> 3;                  // 0..63
  const int bh = (xcd << 2) + (s >> 4);    // 4 bh per XCD -> per-XCD-L2-resident K/V/Q
  const int qchunk = 15 - (s & 15);        // descending q: longest causal work first
  const int w = threadIdx.x >> 6;
  const int lane = threadIdx.x & 63;
  const int li = lane & 15, hi = lane >> 4;
  const int qw0 = (qchunk << 7) + (w << 5);  // this wave's 32 q-rows
  const int b = bh >> 4;

  const unsigned short* Qp = Qb + (size_t)bh * 131072 + (size_t)qw0 * 64;
  const unsigned short* Kp = Kb + (size_t)bh * 131072;
  const unsigned short* Vp = Vt + (size_t)bh * 131072;
  const int* mp = mask + b * 2048;

  // Q as B-operand (col=q=li, k=d): contiguous 16B per lane; 2 groups of 16 q-rows
  bf16x8 qf[2][2];
#pragma unroll
  for (int g = 0; g < 2; ++g) {
    qf[g][0] = ldb8(Qp + (g * 16 + li) * 64 + hi * 8);
    qf[g][1] = ldb8(Qp + (g * 16 + li) * 64 + 32 + hi * 8);
  }

  f32x4 o[2][4];
#pragma unroll
  for (int g = 0; g < 2; ++g)
#pragma unroll
    for (int n = 0; n < 4; ++n) o[g][n] = zero4();
  float m_run[2] = {-FLT_MAX, -FLT_MAX};
  float l_run[2] = {0.f, 0.f};
  const int ntiles = (qw0 >> 5) + 1;  // causal: kv <= qw0+31

  for (int it = 0; it < ntiles; ++it) {
    const int kv0 = it << 5;
    const unsigned short* kp = Kp + (size_t)kv0 * 64;
    // K as A-operand (row=kv=li, k=d) — shared by both q-groups
    const bf16x8 k00 = ldb8(kp + li * 64 + hi * 8);
    const bf16x8 k01 = ldb8(kp + li * 64 + 32 + hi * 8);
    const bf16x8 k10 = ldb8(kp + (16 + li) * 64 + hi * 8);
    const bf16x8 k11 = ldb8(kp + (16 + li) * 64 + 32 + hi * 8);
    const i32x4 mk0 = *reinterpret_cast<const i32x4*>(mp + kv0 + 4 * hi);
    const i32x4 mk1 = *reinterpret_cast<const i32x4*>(mp + kv0 + 16 + 4 * hi);
    // V^T as B-operand (col=d, k=kv) — shared by both q-groups; issue early for overlap
    const bf16x8 vf0 = ldb8(Vp + (size_t)(0 * 16 + li) * 2048 + kv0 + hi * 8);
    const bf16x8 vf1 = ldb8(Vp + (size_t)(1 * 16 + li) * 2048 + kv0 + hi * 8);
    const bf16x8 vf2 = ldb8(Vp + (size_t)(2 * 16 + li) * 2048 + kv0 + hi * 8);
    const bf16x8 vf3 = ldb8(Vp + (size_t)(3 * 16 + li) * 2048 + kv0 + hi * 8);

    bf16x8 pf[2];
#pragma unroll
    for (int g = 0; g < 2; ++g) {
      f32x4 st0 = zero4(), st1 = zero4();
      st0 = __builtin_amdgcn_mfma_f32_16x16x32_bf16(k00, qf[g][0], st0, 0, 0, 0);
      st0 = __builtin_amdgcn_mfma_f32_16x16x32_bf16(k01, qf[g][1], st0, 0, 0, 0);
      st1 = __builtin_amdgcn_mfma_f32_16x16x32_bf16(k10, qf[g][0], st1, 0, 0, 0);
      st1 = __builtin_amdgcn_mfma_f32_16x16x32_bf16(k11, qf[g][1], st1, 0, 0, 0);

      const int q = qw0 + g * 16 + li;
      float p0[4], p1[4];
      float tmax = -FLT_MAX;
#pragma unroll
      for (int r = 0; r < 4; ++r) {
        const int kv = kv0 + 4 * hi + r;
        const float sc = (mk0[r] != 0 && kv <= q) ? st0[r] : -FLT_MAX;
        p0[r] = sc; tmax = fmaxf(tmax, sc);
      }
#pragma unroll
      for (int r = 0; r < 4; ++r) {
        const int kv = kv0 + 16 + 4 * hi + r;
        const float sc = (mk1[r] != 0 && kv <= q) ? st1[r] : -FLT_MAX;
        p1[r] = sc; tmax = fmaxf(tmax, sc);
      }
      // row-max across the 4 lanes sharing q=li
      tmax = fmaxf(tmax, __shfl_xor(tmax, 16, 64));
      tmax = fmaxf(tmax, __shfl_xor(tmax, 32, 64));
      const float m_new = fmaxf(m_run[g], tmax);
      const float resc = __expf(m_run[g] - m_new);  // exp(0)=1 when both -FLT_MAX (all-masked)
      float rsum = 0.f;
#pragma unroll
      for (int r = 0; r < 4; ++r) { p0[r] = __expf(p0[r] - m_new); rsum += p0[r]; }
#pragma unroll
      for (int r = 0; r < 4; ++r) { p1[r] = __expf(p1[r] - m_new); rsum += p1[r]; }
      rsum += __shfl_xor(rsum, 16, 64);
      rsum += __shfl_xor(rsum, 32, 64);
      l_run[g] = l_run[g] * resc + rsum;
      m_run[g] = m_new;

      // rescale O: factor per accumulator row q=4*hi+r, fetched from lane (4*hi+r)
      const float f0 = __shfl(resc, 4 * hi + 0, 64);
      const float f1 = __shfl(resc, 4 * hi + 1, 64);
      const float f2 = __shfl(resc, 4 * hi + 2, 64);
      const float f3 = __shfl(resc, 4 * hi + 3, 64);
#pragma unroll
      for (int n = 0; n < 4; ++n) {
        o[g][n][0] *= f0; o[g][n][1] *= f1; o[g][n][2] *= f2; o[g][n][3] *= f3;
      }

      // P relayout: S^T regs (kv=4*hi+r per 16-tile) -> A-operand (kv=8*hi+e).
      const unsigned pk00 = pack2(p0[0], p0[1]);
      const unsigned pk01 = pack2(p0[2], p0[3]);
      const unsigned pk10 = pack2(p1[0], p1[1]);
      const unsigned pk11 = pack2(p1[2], p1[3]);
      const int s0 = li + ((hi & 1) << 5);
      const int s1 = s0 + 16;
      const unsigned a0 = (unsigned)__shfl((int)pk00, s0, 64);
      const unsigned b0 = (unsigned)__shfl((int)pk10, s0, 64);
      const unsigned a1 = (unsigned)__shfl((int)pk01, s0, 64);
      const unsigned b1 = (unsigned)__shfl((int)pk11, s0, 64);
      const unsigned a2 = (unsigned)__shfl((int)pk00, s1, 64);
      const unsigned b2 = (unsigned)__shfl((int)pk10, s1, 64);
      const unsigned a3 = (unsigned)__shfl((int)pk01, s1, 64);
      const unsigned b3 = (unsigned)__shfl((int)pk11, s1, 64);
      const bool lo = (hi < 2);
      u32x4 pw;
      pw[0] = lo ? a0 : b0;
      pw[1] = lo ? a1 : b1;
      pw[2] = lo ? a2 : b2;
      pw[3] = lo ? a3 : b3;
      pf[g] = __builtin_bit_cast(bf16x8, pw);
    }

#pragma unroll
    for (int g = 0; g < 2; ++g) {
      o[g][0] = __builtin_amdgcn_mfma_f32_16x16x32_bf16(pf[g], vf0, o[g][0], 0, 0, 0);
      o[g][1] = __builtin_amdgcn_mfma_f32_16x16x32_bf16(pf[g], vf1, o[g][1], 0, 0, 0);
      o[g][2] = __builtin_amdgcn_mfma_f32_16x16x32_bf16(pf[g], vf2, o[g][2], 0, 0, 0);
      o[g][3] = __builtin_amdgcn_mfma_f32_16x16x32_bf16(pf[g], vf3, o[g][3], 0, 0, 0);
    }
  }

  // epilogue: normalize; fully-masked rows -> mean(V) (reference uniform-softmax semantics)
  const int h = bh & 15;
#pragma unroll
  for (int g = 0; g < 2; ++g) {
    unsigned short* Op = O + ((size_t)(b * 2048 + qw0 + g * 16)) * 1024 + h * 64;
#pragma unroll
    for (int r = 0; r < 4; ++r) {
      const int qrow = 4 * hi + r;
      const float ls = __shfl(l_run[g], qrow, 64);
      const float mr = __shfl(m_run[g], qrow, 64);
      const bool dead = (mr == -FLT_MAX);
      const float inv = dead ? 0.f : (1.f / ls);
      const float v0 = dead ? Vmean[bh * 64 + 0 + li] : o[g][0][r] * inv;
      const float v1 = dead ? Vmean[bh * 64 + 16 + li] : o[g][1][r] * inv;
      const float v2 = dead ? Vmean[bh * 64 + 32 + li] : o[g][2][r] * inv;
      const float v3 = dead ? Vmean[bh * 64 + 48 + li] : o[g][3][r] * inv;
      unsigned short* row = Op + (size_t)qrow * 1024;
      row[0 + li] = f2bf(v0);
      row[16 + li] = f2bf(v1);
      row[32 + li] = f2bf(v2);
      row[48 + li] = f2bf(v3);
    }
  }
}

extern "C" void kernel_launch(void* const* d_in, const int* in_sizes, int n_in,
                              void* d_out, int out_size, void* d_ws, size_t ws_size,
                              hipStream_t stream) {
  const float* x    = (const float*)d_in[0];
  const float* cond = (const float*)d_in[1];
  const int*   mask = (const int*)d_in[2];
  const float* Wq   = (const float*)d_in[3];
  const float* Wkv  = (const float*)d_in[4];
  const float* Wo   = (const float*)d_in[5];
  const float* bo   = (const float*)d_in[6];
  float* out = (float*)d_out;

  char* ws = (char*)d_ws;
  const size_t MB = 1u << 20;
  unsigned short* xb    = (unsigned short*)(ws + 0 * MB);    // [4096][1024] bf16, 8MB
  unsigned short* condb = (unsigned short*)(ws + 8 * MB);    // [4096][1024] bf16, 8MB
  unsigned short* WqT   = (unsigned short*)(ws + 16 * MB);   // [1024][1024] bf16, 2MB
  unsigned short* WkvT  = (unsigned short*)(ws + 18 * MB);   // [2048][1024] bf16, 4MB
  unsigned short* WoT   = (unsigned short*)(ws + 22 * MB);   // [1024][1024] bf16, 2MB
  unsigned short* Qb    = (unsigned short*)(ws + 24 * MB);   // [32][2048][64] bf16, 8MB
  unsigned short* Kb    = (unsigned short*)(ws + 32 * MB);   // [32][2048][64] bf16, 8MB
  unsigned short* Vt    = (unsigned short*)(ws + 40 * MB);   // [32][64][2048] bf16, 8MB
  unsigned short* Ob    = (unsigned short*)(ws + 48 * MB);   // [4096][1024] bf16, 8MB
  float*          Vmean = (float*)(ws + 56 * MB);            // [32][64] f32, 8KB
  (void)in_sizes; (void)n_in; (void)out_size; (void)ws_size;

  // 1-2: cast activations to bf16
  cast_kernel<<<4096, 256, 0, stream>>>(x, xb, 1048576);
  cast_kernel<<<4096, 256, 0, stream>>>(cond, condb, 1048576);
  // 3-5: transpose+cast weights to [N][K] bf16
  transpose_cast_kernel<<<4096, 256, 0, stream>>>(Wq, WqT, 1024, 1048576);
  transpose_cast_kernel<<<8192, 256, 0, stream>>>(Wkv, WkvT, 2048, 2097152);
  transpose_cast_kernel<<<4096, 256, 0, stream>>>(Wo, WoT, 1024, 1048576);
  // 6: Q projection (scaled)
  gemm_kernel<0><<<dim3(8, 32), 256, 0, stream>>>(xb, WqT, Qb, nullptr, nullptr, nullptr, 1024);
  // 7: KV projection (K normal layout, V transposed)
  gemm_kernel<1><<<dim3(16, 32), 256, 0, stream>>>(condb, WkvT, Kb, Vt, nullptr, nullptr, 1024);
  // 8: V column means (fully-masked-row fallback)
  vmean_kernel<<<32, 256, 0, stream>>>(Vt, Vmean);
  // 9: flash attention (512 blocks: 8 XCD x 4 bh x 16 qchunks, longest-first)
  attn_kernel<<<512, 256, 0, stream>>>(Qb, Kb, Vt, mask, Vmean, Ob);
  // 10: output projection + bias
  gemm_kernel<2><<<dim3(8, 32), 256, 0, stream>>>(Ob, WoT, nullptr, nullptr, out, bo, 1024);
}